// Round 6
// baseline (294.514 us; speedup 1.0000x reference)
//
#include <hip/hip_runtime.h>
#include <hip/hip_bf16.h>

#define BSZ 4096
#define MAXLEN 200
#define EDIM 112
#define NKC 16   // K-chunk partials in big_gemm

typedef __attribute__((ext_vector_type(8))) short bf16x8;
typedef __attribute__((ext_vector_type(4))) float f32x4;

// f32 -> bf16 (RNE), bit-level
static __device__ __forceinline__ short f2bf(float f) {
    unsigned u = __float_as_uint(f);
    unsigned r = (u + 0x7fffu + ((u >> 16) & 1u)) >> 16;
    return (short)r;
}
static __device__ __forceinline__ float bf2f(short s) {
    return __uint_as_float(((unsigned)(unsigned short)s) << 16);
}
static __device__ __forceinline__ bf16x8 cvt8(float4 a, float4 b) {
    bf16x8 r;
    r[0] = f2bf(a.x); r[1] = f2bf(a.y); r[2] = f2bf(a.z); r[3] = f2bf(a.w);
    r[4] = f2bf(b.x); r[5] = f2bf(b.y); r[6] = f2bf(b.z); r[7] = f2bf(b.w);
    return r;
}
static __device__ __forceinline__ unsigned pack2(float a, float b) {
    return ((unsigned)f2bf(a) & 0xffffu) | ((unsigned)f2bf(b) << 16);
}

// Streaming f32 -> bf16; first `zgroups` 8-elem groups are zeros (PAD row).
__global__ __launch_bounds__(256) void f32_to_bf16(const float* __restrict__ src,
                                                   unsigned short* __restrict__ dst,
                                                   int ngroups, int zgroups) {
    int g = blockIdx.x * 256 + threadIdx.x;
    if (g >= ngroups) return;
    bf16x8 o;
    if (g < zgroups) {
        #pragma unroll
        for (int i = 0; i < 8; ++i) o[i] = 0;
    } else {
        const float* p = src + (size_t)(g - zgroups) * 8;
        float4 a = *(const float4*)p;
        float4 b = *(const float4*)(p + 4);
        o = cvt8(a, b);
    }
    *(bf16x8*)(dst + (size_t)g * 8) = o;
}

// Streaming A(f32) -> Asw (bf16 MFMA A-fragments).  grid 2048 x 256 thr:
// wave handles (mtile = blk&255, 4 k32 chunks).  Element mapping identical to
// what big_gemm reads: Asw[((mtile*128+k32)*64+lane)*8 + e] =
// bf16(A[mtile*16 + (lane&15)][k32*32 + (lane>>4)*8 + e]).
__global__ __launch_bounds__(256) void conv_A(const float* __restrict__ Af,
                                              unsigned short* __restrict__ Asw) {
    int wave = threadIdx.x >> 6;
    int lane = threadIdx.x & 63;
    int mtile = blockIdx.x & 255;
    int kg = (blockIdx.x >> 8) * 4 + wave;   // 0..31
    int nrow = lane & 15;
    int quad = lane >> 4;
    const float* row = Af + (size_t)(mtile * 16 + nrow) * 4096;
    #pragma unroll
    for (int i = 0; i < 4; ++i) {
        int k32 = kg * 4 + i;
        const float* p = row + k32 * 32 + quad * 8;
        float4 a0 = *(const float4*)p;
        float4 a1 = *(const float4*)(p + 4);
        *(bf16x8*)(Asw + ((size_t)(mtile * 128 + k32) * 64 + lane) * 8) = cvt8(a0, a1);
    }
}

// bf16-table gather+mean-pool. One block per session; 4 waves x 4 rows/wave,
// 16 B/lane loads; Ebf row 0 is zeros (PAD).  Writes S and inits acc.
__global__ __launch_bounds__(256) void gather_pool_bf(const unsigned short* __restrict__ Ebf,
                                                      const int* __restrict__ items,
                                                      const float* __restrict__ slen,
                                                      float* __restrict__ S,
                                                      float* __restrict__ acc) {
    __shared__ float part[16][14][8];
    int wave = threadIdx.x >> 6;
    int lane = threadIdx.x & 63;
    int b = blockIdx.x;
    int rg = lane / 14;   // 0..3 for lanes 0..55
    int c  = lane % 14;
    const int* it = items + (size_t)b * MAXLEN + wave * 50;
    float a[8];
    #pragma unroll
    for (int e = 0; e < 8; ++e) a[e] = 0.f;
    if (lane < 56) {
        #pragma unroll
        for (int t = 0; t < 13; ++t) {
            int j = t * 4 + rg;
            int idx = 0;
            if (j < 50) idx = it[j];               // idx==0 -> zero row (PAD)
            bf16x8 v = *(const bf16x8*)(Ebf + (size_t)idx * EDIM + c * 8);
            #pragma unroll
            for (int e = 0; e < 8; ++e) a[e] += bf2f(v[e]);
        }
        #pragma unroll
        for (int e = 0; e < 8; ++e) part[wave * 4 + rg][c][e] = a[e];
    }
    __syncthreads();
    int tid = threadIdx.x;
    if (tid < EDIM) {
        int cc = tid >> 3, ee = tid & 7;
        float s = 0.f;
        #pragma unroll
        for (int g = 0; g < 16; ++g) s += part[g][cc][ee];
        s /= slen[b];
        S[(size_t)b * EDIM + tid]   = s;
        acc[(size_t)b * EDIM + tid] = s;
    }
}

// Load 8 consecutive f32 (if valid) -> bf16x8 fragment.
static __device__ __forceinline__ bf16x8 ldcvt(const float* p, bool valid) {
    if (valid) {
        float4 a = *(const float4*)p;
        float4 b = *(const float4*)(p + 4);
        return cvt8(a, b);
    }
    bf16x8 z;
    #pragma unroll
    for (int i = 0; i < 8; ++i) z[i] = 0;
    return z;
}

// Fused {epilogue of previous layer} + {T = Y @ W^T} writing B-operand
// fragments (Bsw).  ONE WAVE per 16 sessions, grid 256 (spread on all CUs).
// MODE 0: Y = S (from gather).  MODE 1: Y = d.*sum(16 Yp partials);
// acc += Y/||Y||; un-normalized Y never leaves the kernel.
// Bsw layout: [(k32*7 + t)*64 + lane] x 8 bf16 -> big_gemm loads lane*16B.
template <int MODE>
__global__ __launch_bounds__(64, 4) void fused_mid(const float* __restrict__ Sin,
                                                   const float* __restrict__ Yp,
                                                   const float* __restrict__ Dm,
                                                   float* __restrict__ accb,
                                                   const float* __restrict__ W,
                                                   unsigned short* __restrict__ Bsw) {
    __shared__ unsigned short Ylds[16][136];  // 4352 B, bank-skewed rows
    int lane = threadIdx.x;
    int gw = blockIdx.x;          // 0..255
    int j0 = gw * 16;
    int nrow = lane & 15;
    int quad = lane >> 4;
    int ses = j0 + nrow;

    // ---- un-normalized Y row `ses`, cols quad*28 .. +27 ----
    float4 v[7];
    if (MODE == 0) {
        const float4* p = (const float4*)(Sin + (size_t)ses * EDIM + quad * 28);
        #pragma unroll
        for (int i = 0; i < 7; ++i) v[i] = p[i];
    } else {
        #pragma unroll
        for (int i = 0; i < 7; ++i) v[i] = make_float4(0.f, 0.f, 0.f, 0.f);
        #pragma unroll 4
        for (int pp = 0; pp < NKC; ++pp) {
            const float4* p = (const float4*)(Yp + (size_t)pp * BSZ * EDIM
                                              + (size_t)ses * EDIM + quad * 28);
            #pragma unroll
            for (int i = 0; i < 7; ++i) {
                float4 t = p[i];
                v[i].x += t.x; v[i].y += t.y; v[i].z += t.z; v[i].w += t.w;
            }
        }
        float d = Dm[(size_t)ses * (BSZ + 1)];   // D diagonal
        float ss = 0.f;
        #pragma unroll
        for (int i = 0; i < 7; ++i) {
            v[i].x *= d; v[i].y *= d; v[i].z *= d; v[i].w *= d;
            ss += v[i].x * v[i].x + v[i].y * v[i].y + v[i].z * v[i].z + v[i].w * v[i].w;
        }
        ss += __shfl_xor(ss, 16, 64);            // reduce across the 4 quads
        ss += __shfl_xor(ss, 32, 64);
        float rinv = 1.f / fmaxf(sqrtf(ss), 1e-12f);
        float4* pa = (float4*)(accb + (size_t)ses * EDIM + quad * 28);
        #pragma unroll
        for (int i = 0; i < 7; ++i) {
            float4 a = pa[i];
            a.x += v[i].x * rinv; a.y += v[i].y * rinv;
            a.z += v[i].z * rinv; a.w += v[i].w * rinv;
            pa[i] = a;
        }
    }

    // ---- bf16 Y tile to LDS (cols 112..127 zeroed for K-padding) ----
    #pragma unroll
    for (int i = 0; i < 7; ++i) {
        uint2 pk;
        pk.x = pack2(v[i].x, v[i].y);
        pk.y = pack2(v[i].z, v[i].w);
        *(uint2*)&Ylds[nrow][quad * 28 + i * 4] = pk;
    }
    *(uint2*)&Ylds[nrow][112 + quad * 4] = make_uint2(0u, 0u);
    __syncthreads();

    // ---- A fragments from LDS ----
    bf16x8 aF[4];
    #pragma unroll
    for (int k32 = 0; k32 < 4; ++k32)
        aF[k32] = *(bf16x8*)&Ylds[nrow][k32 * 32 + quad * 8];

    // ---- MFMA over 7 W-tiles, K = 4 x 32 (cols >=112 zero on both sides) ----
    f32x4 acc[7];
    #pragma unroll
    for (int t = 0; t < 7; ++t) acc[t] = (f32x4){0.f, 0.f, 0.f, 0.f};
    #pragma unroll
    for (int t = 0; t < 7; ++t) {
        const float* wr = W + (size_t)(16 * t + nrow) * EDIM;
        #pragma unroll
        for (int k32 = 0; k32 < 4; ++k32) {
            bf16x8 bF = ldcvt(wr + k32 * 32 + quad * 8, (k32 < 3) || (quad < 2));
            acc[t] = __builtin_amdgcn_mfma_f32_16x16x32_bf16(aF[k32], bF, acc[t], 0, 0, 0);
        }
    }

    // ---- scatter C into Bsw fragment layout ----
    // element (n=16t+nrow, j=j0+quad*4+reg) -> frag(k32=j>>5, t),
    // lane' = ((j>>3)&3)*16 + nrow, elem = j&7
    int k32f = j0 >> 5;
    int qp = ((j0 >> 4) & 1) * 2 + (quad >> 1);
    int e0 = (quad & 1) * 4;
    #pragma unroll
    for (int t = 0; t < 7; ++t) {
        uint2 pk;
        pk.x = pack2(acc[t][0], acc[t][1]);
        pk.y = pack2(acc[t][2], acc[t][3]);
        *(uint2*)(Bsw + ((size_t)(k32f * 7 + t) * 64 + qp * 16 + nrow) * 8 + e0) = pk;
    }
}

// Partial Y = A @ T.  256-thr blocks = 4 INDEPENDENT waves (no LDS/barriers).
// grid 1024: mtile = blk&255 (16-row tile), kc = (blk>>8)*4 + wave (0..15,
// K=256 chunk).  blk = kcg*256+mtile keeps mtile->XCD mapping layer-invariant
// (per-XCD Asw slice ~4 MB = L2).  All loads lane*16B coalesced; 4096 waves
// (16/CU) with unrolled K-loop give the MLP round 5 lacked.
__global__ __launch_bounds__(256, 4) void big_gemm(const unsigned short* __restrict__ Asw,
                                                   const unsigned short* __restrict__ Bsw,
                                                   float* __restrict__ Yp) {
    int wave = threadIdx.x >> 6;
    int lane = threadIdx.x & 63;
    int mtile = blockIdx.x & 255;
    int kc = (blockIdx.x >> 8) * 4 + wave;   // 0..15
    int nrow = lane & 15;
    int quad = lane >> 4;

    f32x4 acc[7];
    #pragma unroll
    for (int t = 0; t < 7; ++t) acc[t] = (f32x4){0.f, 0.f, 0.f, 0.f};

    #pragma unroll
    for (int ks = 0; ks < 8; ++ks) {
        int k32 = kc * 8 + ks;
        bf16x8 aF = *(const bf16x8*)(Asw + ((size_t)(mtile * 128 + k32) * 64 + lane) * 8);
        const unsigned short* bb = Bsw + ((size_t)k32 * 7 * 64 + lane) * 8;
        #pragma unroll
        for (int t = 0; t < 7; ++t) {
            bf16x8 bF = *(const bf16x8*)(bb + (size_t)t * 512);
            acc[t] = __builtin_amdgcn_mfma_f32_16x16x32_bf16(aF, bF, acc[t], 0, 0, 0);
        }
    }

    // C/D: (m = quad*4 + r, n = 16t + nrow); 4x64B segments per store
    float* dst = Yp + (size_t)kc * BSZ * EDIM + (size_t)mtile * 16 * EDIM;
    #pragma unroll
    for (int t = 0; t < 7; ++t)
        #pragma unroll
        for (int r = 0; r < 4; ++r)
            dst[(size_t)(quad * 4 + r) * EDIM + 16 * t + nrow] = acc[t][r];
}

// Final: sum NKC partials, d-scale, normalize, out = (acc + nv) / 4.
__global__ __launch_bounds__(256) void final_epilogue(const float* __restrict__ Yp,
                                                      const float* __restrict__ Dm,
                                                      const float* __restrict__ accb,
                                                      float* __restrict__ out) {
    int wave = threadIdx.x >> 6;
    int lane = threadIdx.x & 63;
    int b = blockIdx.x * 4 + wave;

    float2 v = make_float2(0.f, 0.f);
    size_t o2 = (size_t)b * 56 + lane;
    if (lane < 56) {
        #pragma unroll 4
        for (int p = 0; p < NKC; ++p) {
            float2 t = ((const float2*)(Yp + (size_t)p * BSZ * EDIM))[o2];
            v.x += t.x;
            v.y += t.y;
        }
    }
    float d = Dm[(size_t)b * (BSZ + 1)];
    v.x *= d; v.y *= d;
    float ss = v.x * v.x + v.y * v.y;
    #pragma unroll
    for (int off = 32; off; off >>= 1) ss += __shfl_xor(ss, off, 64);
    float nrm = fmaxf(sqrtf(ss), 1e-12f);
    if (lane < 56) {
        float2 a = ((const float2*)accb)[o2];
        ((float2*)out)[o2] = make_float2((a.x + v.x / nrm) * 0.25f,
                                         (a.y + v.y / nrm) * 0.25f);
    }
}

extern "C" void kernel_launch(void* const* d_in, const int* in_sizes, int n_in,
                              void* d_out, int out_size, void* d_ws, size_t ws_size,
                              hipStream_t stream) {
    (void)in_sizes; (void)n_in; (void)out_size; (void)ws_size;
    const float* emb   = (const float*)d_in[0];
    const float* Dm    = (const float*)d_in[1];
    const float* A     = (const float*)d_in[2];
    const float* slen  = (const float*)d_in[3];
    const float* Ws    = (const float*)d_in[4];
    const int*   items = (const int*)d_in[5];
    float* out = (float*)d_out;

    // workspace layout (16B-aligned), ~92 MB total
    char* w = (char*)d_ws;
    float* Sa   = (float*)w;                                   // 1835008 B
    float* accb = Sa + BSZ * EDIM;                             // 1835008 B
    float* Yp   = accb + BSZ * EDIM;                           // NKC x 1835008 B
    unsigned short* Bsw = (unsigned short*)(Yp + (size_t)NKC * BSZ * EDIM); // 917504 B
    unsigned short* Ebf = Bsw + 128 * 7 * 64 * 8;                   // 22400256 B
    unsigned short* Asw = Ebf + 100001 * EDIM;                      // 33554432 B

    // 1. embedding table -> bf16 (zero PAD row prepended)
    f32_to_bf16<<<5470, 256, 0, stream>>>(emb, Ebf, 1400014, 14);
    // 2. A -> bf16 MFMA fragments (streaming, coalesced)
    conv_A<<<2048, 256, 0, stream>>>(A, Asw);
    // 3. gather + mean-pool -> S, acc
    gather_pool_bf<<<BSZ, 256, 0, stream>>>(Ebf, items, slen, Sa, accb);
    // 4-9. three layers
    fused_mid<0><<<256, 64, 0, stream>>>(Sa, nullptr, nullptr, nullptr, Ws, Bsw);
    big_gemm<<<1024, 256, 0, stream>>>(Asw, Bsw, Yp);
    fused_mid<1><<<256, 64, 0, stream>>>(nullptr, Yp, Dm, accb,
                                         Ws + (size_t)EDIM * EDIM, Bsw);
    big_gemm<<<1024, 256, 0, stream>>>(Asw, Bsw, Yp);
    fused_mid<1><<<256, 64, 0, stream>>>(nullptr, Yp, Dm, accb,
                                         Ws + (size_t)2 * EDIM * EDIM, Bsw);
    big_gemm<<<1024, 256, 0, stream>>>(Asw, Bsw, Yp);
    // 10. final epilogue
    final_epilogue<<<BSZ / 4, 256, 0, stream>>>(Yp, Dm, accb, out);
}

// Round 7
// 288.092 us; speedup vs baseline: 1.0223x; 1.0223x over previous
//
#include <hip/hip_runtime.h>
#include <hip/hip_bf16.h>

#define BSZ 4096
#define MAXLEN 200
#define EDIM 112
#define ERS 128   // padded Ebf row stride (elements)
#define NKC 16    // K-chunk partials in big_gemm

typedef __attribute__((ext_vector_type(8))) short bf16x8;
typedef __attribute__((ext_vector_type(4))) float f32x4;

// f32 -> bf16 (RNE), bit-level
static __device__ __forceinline__ short f2bf(float f) {
    unsigned u = __float_as_uint(f);
    unsigned r = (u + 0x7fffu + ((u >> 16) & 1u)) >> 16;
    return (short)r;
}
static __device__ __forceinline__ float bf2f(short s) {
    return __uint_as_float(((unsigned)(unsigned short)s) << 16);
}
static __device__ __forceinline__ bf16x8 cvt8(float4 a, float4 b) {
    bf16x8 r;
    r[0] = f2bf(a.x); r[1] = f2bf(a.y); r[2] = f2bf(a.z); r[3] = f2bf(a.w);
    r[4] = f2bf(b.x); r[5] = f2bf(b.y); r[6] = f2bf(b.z); r[7] = f2bf(b.w);
    return r;
}
static __device__ __forceinline__ unsigned pack2(float a, float b) {
    return ((unsigned)f2bf(a) & 0xffffu) | ((unsigned)f2bf(b) << 16);
}

// ONE dispatch: Ebf (padded 128-col bf16 table, row 0 = PAD zeros) + Asw
// (bf16 MFMA A-fragments).  blocks [0, NB_E): Ebf; [NB_E, NB_E+2048): Asw.
#define NB_E 6251   // ceil(100001*16 / 256)
__global__ __launch_bounds__(256) void convert_all(const float* __restrict__ emb,
                                                   unsigned short* __restrict__ Ebf,
                                                   const float* __restrict__ Af,
                                                   unsigned short* __restrict__ Asw) {
    if (blockIdx.x < NB_E) {
        // ---- embedding: group g = 16B of row `g>>4`, col-group `g&15` ----
        int g = blockIdx.x * 256 + threadIdx.x;
        if (g >= 100001 * 16) return;
        int row = g >> 4, cg = g & 15;
        bf16x8 o;
        if (row == 0 || cg >= 14) {          // PAD row or 112..127 padding
            #pragma unroll
            for (int i = 0; i < 8; ++i) o[i] = 0;
        } else {
            const float* p = emb + (size_t)(row - 1) * EDIM + cg * 8;
            float4 a = *(const float4*)p;
            float4 b = *(const float4*)(p + 4);
            o = cvt8(a, b);
        }
        *(bf16x8*)(Ebf + (size_t)g * 8) = o;
    } else {
        // ---- A -> Asw fragments: Asw[((mtile*128+k32)*64+lane)*8 + e] =
        //      bf16(A[mtile*16 + (lane&15)][k32*32 + (lane>>4)*8 + e]) ----
        int blk = blockIdx.x - NB_E;          // 0..2047
        int wave = threadIdx.x >> 6;
        int lane = threadIdx.x & 63;
        int mtile = blk & 255;
        int kg = (blk >> 8) * 4 + wave;       // 0..31
        int nrow = lane & 15;
        int quad = lane >> 4;
        const float* row = Af + (size_t)(mtile * 16 + nrow) * 4096;
        #pragma unroll
        for (int i = 0; i < 4; ++i) {
            int k32 = kg * 4 + i;
            const float* p = row + k32 * 32 + quad * 8;
            float4 a0 = *(const float4*)p;
            float4 a1 = *(const float4*)(p + 4);
            *(bf16x8*)(Asw + ((size_t)(mtile * 128 + k32) * 64 + lane) * 8) = cvt8(a0, a1);
        }
    }
}

// Gather+mean-pool on the padded bf16 table.  One block per session; 4 waves,
// each wave pools 50 items, 4 rows/iter x 16 lanes/row x 16B.  Row 0 = zeros,
// so out-of-range j just re-reads the (L1-hot) PAD row — branchless.
__global__ __launch_bounds__(256) void gather_pool_bf(const unsigned short* __restrict__ Ebf,
                                                      const int* __restrict__ items,
                                                      const float* __restrict__ slen,
                                                      float* __restrict__ S,
                                                      float* __restrict__ acc) {
    __shared__ float part[16][ERS];   // 8 KB
    int wave = threadIdx.x >> 6;
    int lane = threadIdx.x & 63;
    int b = blockIdx.x;
    int rg = lane >> 4;   // row within iteration group
    int c  = lane & 15;   // 16B chunk within row
    const int* it = items + (size_t)b * MAXLEN + wave * 50;
    float a[8];
    #pragma unroll
    for (int e = 0; e < 8; ++e) a[e] = 0.f;
    #pragma unroll
    for (int t = 0; t < 13; ++t) {
        int j = t * 4 + rg;                   // 0..51
        int idx = (j < 50) ? it[j] : 0;       // idx==0 -> zero row (PAD)
        bf16x8 v = *(const bf16x8*)(Ebf + (size_t)idx * ERS + c * 8);
        #pragma unroll
        for (int e = 0; e < 8; ++e) a[e] += bf2f(v[e]);
    }
    #pragma unroll
    for (int e = 0; e < 8; ++e) part[wave * 4 + rg][c * 8 + e] = a[e];
    __syncthreads();
    int col = threadIdx.x;
    if (col < EDIM) {
        float s = 0.f;
        #pragma unroll
        for (int g = 0; g < 16; ++g) s += part[g][col];
        s /= slen[b];
        S[(size_t)b * EDIM + col]   = s;
        acc[(size_t)b * EDIM + col] = s;
    }
}

// Load 8 consecutive f32 (if valid) -> bf16x8 fragment.
static __device__ __forceinline__ bf16x8 ldcvt(const float* p, bool valid) {
    if (valid) {
        float4 a = *(const float4*)p;
        float4 b = *(const float4*)(p + 4);
        return cvt8(a, b);
    }
    bf16x8 z;
    #pragma unroll
    for (int i = 0; i < 8; ++i) z[i] = 0;
    return z;
}

// Fused {epilogue of previous layer} + {T = Y @ W^T} writing B-operand
// fragments (Bsw).  ONE WAVE per 16 sessions, grid 256 (spread on all CUs).
// MODE 0: Y = S (from gather).  MODE 1: Y = d.*sum(16 Yp partials);
// acc += Y/||Y||; un-normalized Y never leaves the kernel.
// Bsw layout: [(k32*7 + t)*64 + lane] x 8 bf16 -> big_gemm loads lane*16B.
template <int MODE>
__global__ __launch_bounds__(64, 4) void fused_mid(const float* __restrict__ Sin,
                                                   const float* __restrict__ Yp,
                                                   const float* __restrict__ Dm,
                                                   float* __restrict__ accb,
                                                   const float* __restrict__ W,
                                                   unsigned short* __restrict__ Bsw) {
    __shared__ unsigned short Ylds[16][136];  // 4352 B, bank-skewed rows
    int lane = threadIdx.x;
    int gw = blockIdx.x;          // 0..255
    int j0 = gw * 16;
    int nrow = lane & 15;
    int quad = lane >> 4;
    int ses = j0 + nrow;

    // ---- un-normalized Y row `ses`, cols quad*28 .. +27 ----
    float4 v[7];
    if (MODE == 0) {
        const float4* p = (const float4*)(Sin + (size_t)ses * EDIM + quad * 28);
        #pragma unroll
        for (int i = 0; i < 7; ++i) v[i] = p[i];
    } else {
        #pragma unroll
        for (int i = 0; i < 7; ++i) v[i] = make_float4(0.f, 0.f, 0.f, 0.f);
        #pragma unroll 4
        for (int pp = 0; pp < NKC; ++pp) {
            const float4* p = (const float4*)(Yp + (size_t)pp * BSZ * EDIM
                                              + (size_t)ses * EDIM + quad * 28);
            #pragma unroll
            for (int i = 0; i < 7; ++i) {
                float4 t = p[i];
                v[i].x += t.x; v[i].y += t.y; v[i].z += t.z; v[i].w += t.w;
            }
        }
        float d = Dm[(size_t)ses * (BSZ + 1)];   // D diagonal
        float ss = 0.f;
        #pragma unroll
        for (int i = 0; i < 7; ++i) {
            v[i].x *= d; v[i].y *= d; v[i].z *= d; v[i].w *= d;
            ss += v[i].x * v[i].x + v[i].y * v[i].y + v[i].z * v[i].z + v[i].w * v[i].w;
        }
        ss += __shfl_xor(ss, 16, 64);            // reduce across the 4 quads
        ss += __shfl_xor(ss, 32, 64);
        float rinv = 1.f / fmaxf(sqrtf(ss), 1e-12f);
        float4* pa = (float4*)(accb + (size_t)ses * EDIM + quad * 28);
        #pragma unroll
        for (int i = 0; i < 7; ++i) {
            float4 a = pa[i];
            a.x += v[i].x * rinv; a.y += v[i].y * rinv;
            a.z += v[i].z * rinv; a.w += v[i].w * rinv;
            pa[i] = a;
        }
    }

    // ---- bf16 Y tile to LDS (cols 112..127 zeroed for K-padding) ----
    #pragma unroll
    for (int i = 0; i < 7; ++i) {
        uint2 pk;
        pk.x = pack2(v[i].x, v[i].y);
        pk.y = pack2(v[i].z, v[i].w);
        *(uint2*)&Ylds[nrow][quad * 28 + i * 4] = pk;
    }
    *(uint2*)&Ylds[nrow][112 + quad * 4] = make_uint2(0u, 0u);
    __syncthreads();

    // ---- A fragments from LDS ----
    bf16x8 aF[4];
    #pragma unroll
    for (int k32 = 0; k32 < 4; ++k32)
        aF[k32] = *(bf16x8*)&Ylds[nrow][k32 * 32 + quad * 8];

    // ---- MFMA over 7 W-tiles, K = 4 x 32 (cols >=112 zero on both sides) ----
    f32x4 acc[7];
    #pragma unroll
    for (int t = 0; t < 7; ++t) acc[t] = (f32x4){0.f, 0.f, 0.f, 0.f};
    #pragma unroll
    for (int t = 0; t < 7; ++t) {
        const float* wr = W + (size_t)(16 * t + nrow) * EDIM;
        #pragma unroll
        for (int k32 = 0; k32 < 4; ++k32) {
            bf16x8 bF = ldcvt(wr + k32 * 32 + quad * 8, (k32 < 3) || (quad < 2));
            acc[t] = __builtin_amdgcn_mfma_f32_16x16x32_bf16(aF[k32], bF, acc[t], 0, 0, 0);
        }
    }

    // ---- scatter C into Bsw fragment layout ----
    // element (n=16t+nrow, j=j0+quad*4+reg) -> frag(k32=j>>5, t),
    // lane' = ((j>>3)&3)*16 + nrow, elem = j&7
    int k32f = j0 >> 5;
    int qp = ((j0 >> 4) & 1) * 2 + (quad >> 1);
    int e0 = (quad & 1) * 4;
    #pragma unroll
    for (int t = 0; t < 7; ++t) {
        uint2 pk;
        pk.x = pack2(acc[t][0], acc[t][1]);
        pk.y = pack2(acc[t][2], acc[t][3]);
        *(uint2*)(Bsw + ((size_t)(k32f * 7 + t) * 64 + qp * 16 + nrow) * 8 + e0) = pk;
    }
}

// Partial Y = A @ T.  256-thr blocks = 4 INDEPENDENT waves (no LDS/barriers).
// grid 1024: mtile = blk&255 (16-row tile), kc = (blk>>8)*4 + wave (0..15,
// K=256 chunk).  blk = kcg*256+mtile keeps mtile->XCD mapping layer-invariant
// (per-XCD Asw slice ~4 MB = L2).  All loads lane*16B coalesced.
__global__ __launch_bounds__(256, 4) void big_gemm(const unsigned short* __restrict__ Asw,
                                                   const unsigned short* __restrict__ Bsw,
                                                   float* __restrict__ Yp) {
    int wave = threadIdx.x >> 6;
    int lane = threadIdx.x & 63;
    int mtile = blockIdx.x & 255;
    int kc = (blockIdx.x >> 8) * 4 + wave;   // 0..15
    int nrow = lane & 15;
    int quad = lane >> 4;

    f32x4 acc[7];
    #pragma unroll
    for (int t = 0; t < 7; ++t) acc[t] = (f32x4){0.f, 0.f, 0.f, 0.f};

    #pragma unroll
    for (int ks = 0; ks < 8; ++ks) {
        int k32 = kc * 8 + ks;
        bf16x8 aF = *(const bf16x8*)(Asw + ((size_t)(mtile * 128 + k32) * 64 + lane) * 8);
        const unsigned short* bb = Bsw + ((size_t)k32 * 7 * 64 + lane) * 8;
        #pragma unroll
        for (int t = 0; t < 7; ++t) {
            bf16x8 bF = *(const bf16x8*)(bb + (size_t)t * 512);
            acc[t] = __builtin_amdgcn_mfma_f32_16x16x32_bf16(aF, bF, acc[t], 0, 0, 0);
        }
    }

    // C/D: (m = quad*4 + r, n = 16t + nrow); 4x64B segments per store
    float* dst = Yp + (size_t)kc * BSZ * EDIM + (size_t)mtile * 16 * EDIM;
    #pragma unroll
    for (int t = 0; t < 7; ++t)
        #pragma unroll
        for (int r = 0; r < 4; ++r)
            dst[(size_t)(quad * 4 + r) * EDIM + 16 * t + nrow] = acc[t][r];
}

// Final: sum NKC partials, d-scale, normalize, out = (acc + nv) / 4.
__global__ __launch_bounds__(256) void final_epilogue(const float* __restrict__ Yp,
                                                      const float* __restrict__ Dm,
                                                      const float* __restrict__ accb,
                                                      float* __restrict__ out) {
    int wave = threadIdx.x >> 6;
    int lane = threadIdx.x & 63;
    int b = blockIdx.x * 4 + wave;

    float2 v = make_float2(0.f, 0.f);
    size_t o2 = (size_t)b * 56 + lane;
    if (lane < 56) {
        #pragma unroll 4
        for (int p = 0; p < NKC; ++p) {
            float2 t = ((const float2*)(Yp + (size_t)p * BSZ * EDIM))[o2];
            v.x += t.x;
            v.y += t.y;
        }
    }
    float d = Dm[(size_t)b * (BSZ + 1)];
    v.x *= d; v.y *= d;
    float ss = v.x * v.x + v.y * v.y;
    #pragma unroll
    for (int off = 32; off; off >>= 1) ss += __shfl_xor(ss, off, 64);
    float nrm = fmaxf(sqrtf(ss), 1e-12f);
    if (lane < 56) {
        float2 a = ((const float2*)accb)[o2];
        ((float2*)out)[o2] = make_float2((a.x + v.x / nrm) * 0.25f,
                                         (a.y + v.y / nrm) * 0.25f);
    }
}

extern "C" void kernel_launch(void* const* d_in, const int* in_sizes, int n_in,
                              void* d_out, int out_size, void* d_ws, size_t ws_size,
                              hipStream_t stream) {
    (void)in_sizes; (void)n_in; (void)out_size; (void)ws_size;
    const float* emb   = (const float*)d_in[0];
    const float* Dm    = (const float*)d_in[1];
    const float* A     = (const float*)d_in[2];
    const float* slen  = (const float*)d_in[3];
    const float* Ws    = (const float*)d_in[4];
    const int*   items = (const int*)d_in[5];
    float* out = (float*)d_out;

    // workspace layout (16B-aligned), ~96 MB total
    char* w = (char*)d_ws;
    float* Sa   = (float*)w;                                   // 1835008 B
    float* accb = Sa + BSZ * EDIM;                             // 1835008 B
    float* Yp   = accb + BSZ * EDIM;                           // NKC x 1835008 B
    unsigned short* Bsw = (unsigned short*)(Yp + (size_t)NKC * BSZ * EDIM); // 917504 B
    unsigned short* Ebf = Bsw + 128 * 7 * 64 * 8;              // 100001*128*2 = 25600256 B
    unsigned short* Asw = Ebf + (size_t)100001 * ERS;          // 33554432 B

    // 1. one dispatch: emb -> Ebf (padded, PAD row 0) AND A -> Asw fragments
    convert_all<<<NB_E + 2048, 256, 0, stream>>>(emb, Ebf, A, Asw);
    // 2. gather + mean-pool -> S, acc
    gather_pool_bf<<<BSZ, 256, 0, stream>>>(Ebf, items, slen, Sa, accb);
    // 3-8. three layers
    fused_mid<0><<<256, 64, 0, stream>>>(Sa, nullptr, nullptr, nullptr, Ws, Bsw);
    big_gemm<<<1024, 256, 0, stream>>>(Asw, Bsw, Yp);
    fused_mid<1><<<256, 64, 0, stream>>>(nullptr, Yp, Dm, accb,
                                         Ws + (size_t)EDIM * EDIM, Bsw);
    big_gemm<<<1024, 256, 0, stream>>>(Asw, Bsw, Yp);
    fused_mid<1><<<256, 64, 0, stream>>>(nullptr, Yp, Dm, accb,
                                         Ws + (size_t)2 * EDIM * EDIM, Bsw);
    big_gemm<<<1024, 256, 0, stream>>>(Asw, Bsw, Yp);
    // 9. final epilogue
    final_epilogue<<<BSZ / 4, 256, 0, stream>>>(Yp, Dm, accb, out);
}